// Round 1
// baseline (699.823 us; speedup 1.0000x reference)
//
#include <hip/hip_runtime.h>

#define NB 512
#define NL 64
#define NH 128
#define NT 128
#define NENT 200000

typedef __attribute__((ext_vector_type(8))) __bf16 bf16x8;
typedef __attribute__((ext_vector_type(4))) float f32x4;

__device__ __forceinline__ unsigned short f32_bf16_rne(float f) {
    unsigned int u = __float_as_uint(f);
    u += 0x7fffu + ((u >> 16) & 1u);
    return (unsigned short)(u >> 16);
}

// ---------------------------------------------------------------------------
// Kernel 1: per-batch prep. One block per batch b (512 blocks x 512 threads).
// Computes q, cond_in, cond_gate, hist features, x, a, scan, attention,
// and writes V[b][h] = (q + context) * rel   as bf16 to workspace.
// LDS ~136 KB -> 1 block/CU.
// ---------------------------------------------------------------------------
extern "C" __global__ void __launch_bounds__(512)
prep_kernel(const int* __restrict__ heads, const int* __restrict__ rels,
            const int* __restrict__ times, const int* __restrict__ hist_e,
            const int* __restrict__ hist_r, const float* __restrict__ hist_d,
            const float* __restrict__ hist_m, const float* __restrict__ ent,
            const float* __restrict__ rele, const float* __restrict__ tim,
            const float* __restrict__ dW, const float* __restrict__ db,
            const float* __restrict__ qW, const float* __restrict__ qb,
            const float* __restrict__ inW, const float* __restrict__ inb,
            const float* __restrict__ aW, const float* __restrict__ ab,
            const float* __restrict__ hiW, const float* __restrict__ hib,
            const float* __restrict__ hgW, const float* __restrict__ hgb,
            const float* __restrict__ attnW, const float* __restrict__ attnb,
            unsigned short* __restrict__ Vb)
{
    const int b = blockIdx.x;
    const int t = threadIdx.x;

    __shared__ float s_qin[384];                 // [head | rel | tfeat]
    __shared__ float s_q[128], s_ci[128], s_cg[128];
    __shared__ float s_aw[256];
    __shared__ float s_dW[128], s_db2[128];
    __shared__ int   s_he[64], s_hr[64];
    __shared__ float s_hd[64], s_m[64];
    __shared__ float s_x[64 * 128];
    __shared__ float s_reg[64 * 384];            // hist_in; later aliased: a [0,8192), h [8192,8192+64*132)
    __shared__ float s_attn[64];
    __shared__ float s_red[512];
    __shared__ float s_qdot;

    // ---- stage small vectors ----
    {
        const int head = heads[b];
        const int rl   = rels[b];
        const int tm   = times[b];
        if (t < 384) {
            float v;
            if (t < 128)      v = ent[(long)head * NH + t];
            else if (t < 256) v = rele[rl * NH + (t - 128)];
            else              v = tim[tm * NT + (t - 256)];
            s_qin[t] = v;
        }
        if (t < 256) s_aw[t] = attnW[t];
        if (t >= 384) { const int i = t - 384; s_dW[i] = dW[i]; s_db2[i] = db[i]; }
        if (t < 64) {
            s_he[t] = hist_e[b * NL + t];
            s_hr[t] = hist_r[b * NL + t];
            s_hd[t] = hist_d[b * NL + t];
            s_m[t]  = hist_m[b * NL + t];
        }
    }
    __syncthreads();

    // ---- gather history features into s_reg[l][384] = [ne | re | df] ----
    for (int idx = t; idx < 64 * 96; idx += 512) {
        const int l = idx / 96, c = idx % 96;
        float4 v;
        if (c < 32) {
            v = *reinterpret_cast<const float4*>(ent + (long)s_he[l] * NH + c * 4);
        } else if (c < 64) {
            v = *reinterpret_cast<const float4*>(rele + s_hr[l] * NH + (c - 32) * 4);
        } else {
            const int k = (c - 64) * 4;
            const float d = s_hd[l];
            v.x = fmaf(d, s_dW[k + 0], s_db2[k + 0]);
            v.y = fmaf(d, s_dW[k + 1], s_db2[k + 1]);
            v.z = fmaf(d, s_dW[k + 2], s_db2[k + 2]);
            v.w = fmaf(d, s_dW[k + 3], s_db2[k + 3]);
        }
        *reinterpret_cast<float4*>(s_reg + l * 384 + c * 4) = v;
    }

    // ---- q / cond_in / cond_gate (weights stream from L2, coalesced over lanes) ----
    if (t < 128) {
        float acc = qb[t];
        for (int k = 0; k < 384; ++k) acc = fmaf(s_qin[k], qW[k * NH + t], acc);
        s_q[t] = acc;
    } else if (t < 256) {
        const int j = t - 128;
        float acc = hib[j];
        for (int k = 0; k < 128; ++k) acc = fmaf(s_qin[128 + k], hiW[k * NH + j], acc);
        s_ci[j] = acc;
    } else if (t < 384) {
        const int j = t - 256;
        float acc = hgb[j];
        for (int k = 0; k < 128; ++k) acc = fmaf(s_qin[128 + k], hgW[k * NH + j], acc);
        s_cg[j] = 1.f / (1.f + expf(-acc));
    }
    __syncthreads();

    // ---- GEMM1: x[l][j] = hist_in[l] . in_W[:,j] + in_b[j] + cond_in[j] ----
    // thread -> 4 j's (j4..j4+3) x 4 l's (lg + 16*i)
    {
        const int jq = t & 31, lg = t >> 5;
        const int j4 = jq * 4;
        const float b0 = inb[j4 + 0] + s_ci[j4 + 0];
        const float b1 = inb[j4 + 1] + s_ci[j4 + 1];
        const float b2 = inb[j4 + 2] + s_ci[j4 + 2];
        const float b3 = inb[j4 + 3] + s_ci[j4 + 3];
        float acc[4][4];
        #pragma unroll
        for (int i = 0; i < 4; ++i) { acc[i][0] = b0; acc[i][1] = b1; acc[i][2] = b2; acc[i][3] = b3; }
        for (int k = 0; k < 384; ++k) {
            const float4 wv = *reinterpret_cast<const float4*>(inW + k * NH + j4);
            #pragma unroll
            for (int i = 0; i < 4; ++i) {
                const float h = s_reg[(lg + 16 * i) * 384 + k];
                acc[i][0] = fmaf(h, wv.x, acc[i][0]);
                acc[i][1] = fmaf(h, wv.y, acc[i][1]);
                acc[i][2] = fmaf(h, wv.z, acc[i][2]);
                acc[i][3] = fmaf(h, wv.w, acc[i][3]);
            }
        }
        #pragma unroll
        for (int i = 0; i < 4; ++i) {
            *reinterpret_cast<float4*>(s_x + (lg + 16 * i) * NH + j4) =
                make_float4(acc[i][0], acc[i][1], acc[i][2], acc[i][3]);
        }
    }
    __syncthreads();

    // ---- GEMM2: a = sigmoid(x @ a_W + a_b), stored into s_reg[0..8192) ----
    {
        const int jq = t & 31, lg = t >> 5;
        const int j4 = jq * 4;
        float acc[4][4];
        #pragma unroll
        for (int i = 0; i < 4; ++i) {
            acc[i][0] = ab[j4 + 0]; acc[i][1] = ab[j4 + 1];
            acc[i][2] = ab[j4 + 2]; acc[i][3] = ab[j4 + 3];
        }
        for (int k = 0; k < 128; ++k) {
            const float4 wv = *reinterpret_cast<const float4*>(aW + k * NH + j4);
            #pragma unroll
            for (int i = 0; i < 4; ++i) {
                const float xv = s_x[(lg + 16 * i) * NH + k];
                acc[i][0] = fmaf(xv, wv.x, acc[i][0]);
                acc[i][1] = fmaf(xv, wv.y, acc[i][1]);
                acc[i][2] = fmaf(xv, wv.z, acc[i][2]);
                acc[i][3] = fmaf(xv, wv.w, acc[i][3]);
            }
        }
        #pragma unroll
        for (int i = 0; i < 4; ++i) {
            const int row = (lg + 16 * i) * NH + j4;
            s_reg[row + 0] = 1.f / (1.f + expf(-acc[i][0]));
            s_reg[row + 1] = 1.f / (1.f + expf(-acc[i][1]));
            s_reg[row + 2] = 1.f / (1.f + expf(-acc[i][2]));
            s_reg[row + 3] = 1.f / (1.f + expf(-acc[i][3]));
        }
    }
    __syncthreads();

    // ---- scan over L (threads 0-127, one column each); qdot partials on 128-255 ----
    float* const s_a = s_reg;
    float* const s_h = s_reg + 64 * NH;          // stride 132 (padded, conflict-free)
    if (t < 128) {
        float h = 0.f;
        const float cg = s_cg[t];
        for (int l = 0; l < 64; ++l) {
            const float xt = s_x[l * NH + t];
            const float at = s_a[l * NH + t];
            const float mt = s_m[l];
            const float hn = at * h + (1.f - at) * xt;
            h = mt * hn + (1.f - mt) * h;
            s_h[l * 132 + t] = h * cg;           // history_seq = hseq * cond_gate
        }
    } else if (t < 256) {
        const int i = t - 128;
        s_red[i] = s_q[i] * s_aw[128 + i];
    }
    __syncthreads();
    if (t == 0) {
        float acc = 0.f;
        for (int i = 0; i < 128; ++i) acc += s_red[i];
        s_qdot = acc + attnb[0];
    }
    __syncthreads();

    // ---- attention scores: partials over h-chunks ----
    {
        const int l = t >> 3, c = t & 7;
        const int h0 = c * 16;
        float p = 0.f;
        #pragma unroll
        for (int hh = 0; hh < 16; ++hh) p = fmaf(s_h[l * 132 + h0 + hh], s_aw[h0 + hh], p);
        s_red[t] = p;
    }
    __syncthreads();

    // ---- finalize scores + masked softmax (wave 0) ----
    if (t < 64) {
        float s = s_qdot;
        #pragma unroll
        for (int c = 0; c < 8; ++c) s += s_red[t * 8 + c];
        s = tanhf(s);
        if (s_m[t] <= 0.f) s = -1e9f;
        float mx = s;
        #pragma unroll
        for (int off = 32; off > 0; off >>= 1) mx = fmaxf(mx, __shfl_xor(mx, off, 64));
        const float e = expf(s - mx);
        float den = e;
        #pragma unroll
        for (int off = 32; off > 0; off >>= 1) den += __shfl_xor(den, off, 64);
        float p = (e / den) * s_m[t];
        float s2 = p;
        #pragma unroll
        for (int off = 32; off > 0; off >>= 1) s2 += __shfl_xor(s2, off, 64);
        p = p / fmaxf(s2, 1e-9f);
        s_attn[t] = p;
    }
    __syncthreads();

    // ---- context, rep, V = (q+context)*rel  ->  bf16 ----
    if (t < 128) {
        float ctx = 0.f;
        for (int l = 0; l < 64; ++l) ctx = fmaf(s_h[l * 132 + t], s_attn[l], ctx);
        const float rep = s_q[t] + ctx;
        const float v = rep * s_qin[128 + t];    // * rel
        Vb[b * NH + t] = f32_bf16_rne(v);
    }
}

// ---------------------------------------------------------------------------
// Kernel 2: out[512, 200000] = V @ E^T via bf16 MFMA, fp32 accumulate.
// Block = 64 entities x all 512 b. 4 waves, wave w -> b in [w*128, w*128+128).
// Entity mapping e = eb + 4*(lane&15) + et  =>  per-lane float4 stores.
// E converted fp32->bf16 (RNE) in-register; no extra HBM pass.
// ---------------------------------------------------------------------------
extern "C" __global__ void __launch_bounds__(256)
entity_gemm(const float* __restrict__ E, const unsigned short* __restrict__ Vb,
            float* __restrict__ out)
{
    const int lane = threadIdx.x & 63;
    const int w    = threadIdx.x >> 6;
    const int n    = lane & 15;
    const int quad = lane >> 4;
    const long eb  = (long)blockIdx.x * 64;
    const int bbase = w * 128;

    f32x4 acc[8][4];
    #pragma unroll
    for (int i = 0; i < 8; ++i)
        #pragma unroll
        for (int j = 0; j < 4; ++j) acc[i][j] = (f32x4){0.f, 0.f, 0.f, 0.f};

    #pragma unroll 1
    for (int ks = 0; ks < 4; ++ks) {
        const int k0 = ks * 32 + quad * 8;       // A[m][k]: m=lane&15, k=quad*8+j
        bf16x8 Af[8];
        #pragma unroll
        for (int bt = 0; bt < 8; ++bt) {
            const int br = bbase + bt * 16 + n;
            Af[bt] = *reinterpret_cast<const bf16x8*>(Vb + br * NH + k0);
        }
        bf16x8 Bf[4];
        #pragma unroll
        for (int et = 0; et < 4; ++et) {
            const long er = eb + n * 4 + et;     // B[k][n] = E[e(n)][k]
            const float* p = E + er * NH + k0;
            const float4 x0 = *reinterpret_cast<const float4*>(p);
            const float4 x1 = *reinterpret_cast<const float4*>(p + 4);
            union { bf16x8 v; unsigned short u[8]; } tmp;
            tmp.u[0] = f32_bf16_rne(x0.x); tmp.u[1] = f32_bf16_rne(x0.y);
            tmp.u[2] = f32_bf16_rne(x0.z); tmp.u[3] = f32_bf16_rne(x0.w);
            tmp.u[4] = f32_bf16_rne(x1.x); tmp.u[5] = f32_bf16_rne(x1.y);
            tmp.u[6] = f32_bf16_rne(x1.z); tmp.u[7] = f32_bf16_rne(x1.w);
            Bf[et] = tmp.v;
        }
        #pragma unroll
        for (int bt = 0; bt < 8; ++bt)
            #pragma unroll
            for (int et = 0; et < 4; ++et)
                acc[bt][et] = __builtin_amdgcn_mfma_f32_16x16x32_bf16(
                    Af[bt], Bf[et], acc[bt][et], 0, 0, 0);
    }

    // C/D layout: col = lane&15 (-> n), row = quad*4 + r (-> b within tile)
    #pragma unroll
    for (int bt = 0; bt < 8; ++bt) {
        #pragma unroll
        for (int r = 0; r < 4; ++r) {
            const int b = bbase + bt * 16 + quad * 4 + r;
            const float4 v = make_float4(acc[bt][0][r], acc[bt][1][r],
                                         acc[bt][2][r], acc[bt][3][r]);
            *reinterpret_cast<float4*>(out + (long)b * NENT + eb + n * 4) = v;
        }
    }
}

extern "C" void kernel_launch(void* const* d_in, const int* in_sizes, int n_in,
                              void* d_out, int out_size, void* d_ws, size_t ws_size,
                              hipStream_t stream) {
    const int*   heads   = (const int*)d_in[0];
    const int*   rels    = (const int*)d_in[1];
    const int*   times_p = (const int*)d_in[2];
    const int*   hist_e  = (const int*)d_in[3];
    const int*   hist_r  = (const int*)d_in[4];
    const float* hist_d  = (const float*)d_in[5];
    const float* hist_m  = (const float*)d_in[6];
    const float* ent     = (const float*)d_in[7];
    const float* rele    = (const float*)d_in[8];
    const float* tim     = (const float*)d_in[9];
    const float* dW      = (const float*)d_in[10];
    const float* db      = (const float*)d_in[11];
    const float* qW      = (const float*)d_in[12];
    const float* qb      = (const float*)d_in[13];
    const float* inW     = (const float*)d_in[14];
    const float* inb     = (const float*)d_in[15];
    const float* aW      = (const float*)d_in[16];
    const float* ab      = (const float*)d_in[17];
    const float* hiW     = (const float*)d_in[18];
    const float* hib     = (const float*)d_in[19];
    const float* hgW     = (const float*)d_in[20];
    const float* hgb     = (const float*)d_in[21];
    const float* attnW   = (const float*)d_in[22];
    const float* attnb   = (const float*)d_in[23];

    unsigned short* Vb = (unsigned short*)d_ws;  // 512*128 bf16 = 128 KB
    float* out = (float*)d_out;

    prep_kernel<<<dim3(NB), dim3(512), 0, stream>>>(
        heads, rels, times_p, hist_e, hist_r, hist_d, hist_m, ent, rele, tim,
        dW, db, qW, qb, inW, inb, aW, ab, hiW, hib, hgW, hgb, attnW, attnb, Vb);

    entity_gemm<<<dim3(NENT / 64), dim3(256), 0, stream>>>(ent, Vb, out);
}